// Round 2
// baseline (477.109 us; speedup 1.0000x reference)
//
#include <hip/hip_runtime.h>
#include <hip/hip_bf16.h>

#define D 64

// flags[0] = 1 if float tensors are fp32 (else bf16)
// flags[1] = 1 if edge_index is int64 (else int32)

__device__ __forceinline__ float bf16u_to_f32(unsigned short u) {
  union { unsigned int i; float f; } c;
  c.i = ((unsigned int)u) << 16;
  return c.f;
}

__global__ void k_probe(const void* W, const void* ei, int* flags) {
  if (threadIdx.x == 0 && blockIdx.x == 0) {
    const unsigned short* wb = (const unsigned short*)W;
    int big = 0;
    for (int i = 0; i < 512; i++) {
      float v = bf16u_to_f32(wb[i]);
      if (!(fabsf(v) < 100.f)) big = 1;  // NaN also lands here
    }
    flags[0] = big;  // huge magnitudes => data is actually fp32
    const int* e32 = (const int*)ei;
    int anynz = 0;
    for (int i = 1; i < 128; i += 2)
      if (e32[i] != 0) anynz = 1;
    flags[1] = anynz ? 0 : 1;  // all-zero odd slots => int64
  }
}

// ---------------- setup kernels (CSR build + norm) ----------------

__global__ __launch_bounds__(256) void k_count(const void* __restrict__ ei,
                                               const int* __restrict__ flags,
                                               int* __restrict__ deg, int e) {
  int i64 = flags[1];
  int i = blockIdx.x * blockDim.x + threadIdx.x;
  int stride = gridDim.x * blockDim.x;
  if (i64) {
    const long long* dst = (const long long*)ei + e;
    for (; i < e; i += stride) atomicAdd(&deg[(int)dst[i]], 1);
  } else {
    const int* dst = (const int*)ei + e;
    for (; i < e; i += stride) atomicAdd(&deg[dst[i]], 1);
  }
}

#define SCAN_BLOCK 256
#define SCAN_ITEMS 4
__global__ __launch_bounds__(SCAN_BLOCK) void k_local_scan(
    const int* __restrict__ deg, int* __restrict__ row_ptr,
    int* __restrict__ partials, int n) {
  __shared__ int lds[SCAN_BLOCK];
  int base = blockIdx.x * (SCAN_BLOCK * SCAN_ITEMS);
  int t = threadIdx.x;
  int v[SCAN_ITEMS];
  int s = 0;
#pragma unroll
  for (int i = 0; i < SCAN_ITEMS; i++) {
    int idx = base + t * SCAN_ITEMS + i;
    v[i] = (idx < n) ? deg[idx] : 0;
    s += v[i];
  }
  lds[t] = s;
  __syncthreads();
  for (int off = 1; off < SCAN_BLOCK; off <<= 1) {
    int tv = (t >= off) ? lds[t - off] : 0;
    __syncthreads();
    lds[t] += tv;
    __syncthreads();
  }
  int incl = lds[t];
  int excl = incl - s;
  if (t == SCAN_BLOCK - 1) partials[blockIdx.x] = incl;
  int run = excl;
#pragma unroll
  for (int i = 0; i < SCAN_ITEMS; i++) {
    int idx = base + t * SCAN_ITEMS + i;
    if (idx < n) row_ptr[idx] = run;
    run += v[i];
  }
}

__global__ __launch_bounds__(256) void k_scan_partials(int* partials, int nb) {
  __shared__ int lds[256];
  int t = threadIdx.x;
  int v = (t < nb) ? partials[t] : 0;
  lds[t] = v;
  __syncthreads();
  for (int off = 1; off < 256; off <<= 1) {
    int tv = (t >= off) ? lds[t - off] : 0;
    __syncthreads();
    lds[t] += tv;
    __syncthreads();
  }
  if (t < nb) partials[t] = lds[t] - v;
}

__global__ __launch_bounds__(256) void k_finalize(
    int* __restrict__ row_ptr, const int* __restrict__ partials,
    int* __restrict__ cursor, const int* __restrict__ deg,
    float* __restrict__ dinv, int n, int e) {
  int i = blockIdx.x * blockDim.x + threadIdx.x;
  if (i < n) {
    int rp = row_ptr[i] + partials[i >> 10];
    row_ptr[i] = rp;
    cursor[i] = rp;
    dinv[i] = rsqrtf((float)(deg[i] + 1));  // +1 = self loop
    if (i == 0) row_ptr[n] = e;
  }
}

__global__ __launch_bounds__(256) void k_scatter(const void* __restrict__ ei,
                                                 const int* __restrict__ flags,
                                                 int* __restrict__ cursor,
                                                 int* __restrict__ csr, int e) {
  int i64 = flags[1];
  int i = blockIdx.x * blockDim.x + threadIdx.x;
  int stride = gridDim.x * blockDim.x;
  if (i64) {
    const long long* src = (const long long*)ei;
    const long long* dst = src + e;
    for (; i < e; i += stride) {
      int pos = atomicAdd(&cursor[(int)dst[i]], 1);
      csr[pos] = (int)src[i];
    }
  } else {
    const int* src = (const int*)ei;
    const int* dst = src + e;
    for (; i < e; i += stride) {
      int pos = atomicAdd(&cursor[dst[i]], 1);
      csr[pos] = src[i];
    }
  }
}

__global__ __launch_bounds__(256) void k_load_x(const void* __restrict__ in,
                                                const int* __restrict__ flags,
                                                float* __restrict__ out,
                                                int n) {
  int f32 = flags[0];
  int i = blockIdx.x * blockDim.x + threadIdx.x;
  int stride = gridDim.x * blockDim.x;
  if (f32) {
    const float* p = (const float*)in;
    for (; i < n; i += stride) out[i] = p[i];
  } else {
    const __hip_bfloat16* p = (const __hip_bfloat16*)in;
    for (; i < n; i += stride) out[i] = __bfloat162float(p[i]);
  }
}

// ---------------- compute kernels ----------------

// One wave per row (grid-strided). Lane j holds W[:,j] in 64 VGPRs.
// outf = dinv[row] * (x@W), all fp32 internal. Wb/Wf are the bf16-offset and
// fp32-offset candidate pointers for this layer's weights; flag picks.
__global__ __launch_bounds__(256) void k_matmul2(
    const float* __restrict__ x, const void* __restrict__ Wb,
    const void* __restrict__ Wf, const float* __restrict__ dinv,
    float* __restrict__ outf, const int* __restrict__ flags, int nrows) {
  int f32 = flags[0];
  int lane = threadIdx.x & 63;
  int wid = threadIdx.x >> 6;
  float w[D];
  if (f32) {
    const float* W = (const float*)Wf;
#pragma unroll
    for (int k = 0; k < D; k++) w[k] = W[k * D + lane];
  } else {
    const __hip_bfloat16* W = (const __hip_bfloat16*)Wb;
#pragma unroll
    for (int k = 0; k < D; k++) w[k] = __bfloat162float(W[k * D + lane]);
  }

  int wave = blockIdx.x * 4 + wid;
  int nwaves = gridDim.x * 4;
  for (int row = wave; row < nrows; row += nwaves) {
    int ur = __builtin_amdgcn_readfirstlane(row);
    const float* xr = x + (size_t)ur * D;
    float a0 = 0.f, a1 = 0.f, a2 = 0.f, a3 = 0.f;
#pragma unroll
    for (int k = 0; k < D; k += 4) {
      a0 = fmaf(xr[k + 0], w[k + 0], a0);
      a1 = fmaf(xr[k + 1], w[k + 1], a1);
      a2 = fmaf(xr[k + 2], w[k + 2], a2);
      a3 = fmaf(xr[k + 3], w[k + 3], a3);
    }
    float acc = (a0 + a1) + (a2 + a3);
    outf[(size_t)ur * D + lane] = dinv[ur] * acc;
  }
}

// Final projection: out = x@W + b, store dtype picked by flag.
__global__ __launch_bounds__(256) void k_matmul_final(
    const float* __restrict__ x, const void* __restrict__ W,
    const void* __restrict__ bias, void* __restrict__ out,
    const int* __restrict__ flags, int nrows) {
  int f32 = flags[0];
  int lane = threadIdx.x & 63;
  int wid = threadIdx.x >> 6;
  float w[D];
  float b;
  if (f32) {
    const float* Wf = (const float*)W;
#pragma unroll
    for (int k = 0; k < D; k++) w[k] = Wf[k * D + lane];
    b = ((const float*)bias)[lane];
  } else {
    const __hip_bfloat16* Wb = (const __hip_bfloat16*)W;
#pragma unroll
    for (int k = 0; k < D; k++) w[k] = __bfloat162float(Wb[k * D + lane]);
    b = __bfloat162float(((const __hip_bfloat16*)bias)[lane]);
  }

  int wave = blockIdx.x * 4 + wid;
  int nwaves = gridDim.x * 4;
  for (int row = wave; row < nrows; row += nwaves) {
    int ur = __builtin_amdgcn_readfirstlane(row);
    const float* xr = x + (size_t)ur * D;
    float a0 = 0.f, a1 = 0.f, a2 = 0.f, a3 = 0.f;
#pragma unroll
    for (int k = 0; k < D; k += 4) {
      a0 = fmaf(xr[k + 0], w[k + 0], a0);
      a1 = fmaf(xr[k + 1], w[k + 1], a1);
      a2 = fmaf(xr[k + 2], w[k + 2], a2);
      a3 = fmaf(xr[k + 3], w[k + 3], a3);
    }
    float r = (a0 + a1) + (a2 + a3) + b;
    size_t idx = (size_t)ur * D + lane;
    if (f32)
      ((float*)out)[idx] = r;
    else
      ((__hip_bfloat16*)out)[idx] = __float2bfloat16(r);
  }
}

// One wave per node, lane = feature. acc = hp[node] (self loop) + sum of
// hp[src] over incoming CSR edges; x' = relu(dinv[node]*acc + bias).
__global__ __launch_bounds__(256) void k_agg2(
    const float* __restrict__ hp, const int* __restrict__ row_ptr,
    const int* __restrict__ csr, const float* __restrict__ dinv,
    const void* __restrict__ bias_b, const void* __restrict__ bias_f,
    const int* __restrict__ flags, float* __restrict__ xout, int n) {
  int f32 = flags[0];
  int lane = threadIdx.x & 63;
  int wid = threadIdx.x >> 6;
  int node = blockIdx.x * 4 + wid;
  if (node >= n) return;
  int un = __builtin_amdgcn_readfirstlane(node);

  float b = f32 ? ((const float*)bias_f)[lane]
                : __bfloat162float(((const __hip_bfloat16*)bias_b)[lane]);

  float acc = hp[(size_t)un * D + lane];  // self loop
  int s0 = row_ptr[un];
  int s1 = row_ptr[un + 1];
  int i = s0;
  for (; i + 1 < s1; i += 2) {  // unroll x2 for gather ILP
    int a = csr[i];
    int c = csr[i + 1];
    float va = hp[(size_t)a * D + lane];
    float vc = hp[(size_t)c * D + lane];
    acc += va;
    acc += vc;
  }
  if (i < s1) acc += hp[(size_t)csr[i] * D + lane];

  float v = fmaf(dinv[un], acc, b);
  xout[(size_t)un * D + lane] = fmaxf(v, 0.f);
}

// ---------------- launch ----------------

extern "C" void kernel_launch(void* const* d_in, const int* in_sizes, int n_in,
                              void* d_out, int out_size, void* d_ws,
                              size_t ws_size, hipStream_t stream) {
  const void* x0 = d_in[0];
  const void* ei = d_in[1];
  const char* Ws = (const char*)d_in[2];
  const char* bs = (const char*)d_in[3];
  const void* Wout = d_in[4];
  const void* bout = d_in[5];

  const int N = in_sizes[0] / D;  // 100000
  const int E = in_sizes[1] / 2;  // 1000000
  const int NB = (N + 1023) / 1024;

  char* p = (char*)d_ws;
  auto alloc = [&](size_t bytes) {
    char* r = p;
    p += (bytes + 511) & ~(size_t)511;
    return r;
  };
  int* flags = (int*)alloc(8);
  int* deg = (int*)alloc((size_t)N * 4);
  int* row_ptr = (int*)alloc((size_t)(N + 1) * 4);
  int* cursor = (int*)alloc((size_t)N * 4);
  int* partials = (int*)alloc(1024);
  int* csr = (int*)alloc((size_t)E * 4);
  float* dinv = (float*)alloc((size_t)N * 4);
  float* hp = (float*)alloc((size_t)N * D * 4);
  float* xbuf = (float*)alloc((size_t)N * D * 4);
  (void)ws_size;
  (void)n_in;
  (void)out_size;

  hipMemsetAsync(deg, 0, (size_t)N * 4, stream);

  k_probe<<<1, 64, 0, stream>>>(Ws, ei, flags);
  k_count<<<1024, 256, 0, stream>>>(ei, flags, deg, E);
  k_local_scan<<<NB, 256, 0, stream>>>(deg, row_ptr, partials, N);
  k_scan_partials<<<1, 256, 0, stream>>>(partials, NB);
  k_finalize<<<(N + 255) / 256, 256, 0, stream>>>(row_ptr, partials, cursor,
                                                  deg, dinv, N, E);
  k_scatter<<<1024, 256, 0, stream>>>(ei, flags, cursor, csr, E);
  k_load_x<<<2048, 256, 0, stream>>>(x0, flags, xbuf, N * D);

  const size_t WSZ = (size_t)D * D;
  for (int l = 0; l < 3; ++l) {
    const void* W_b = Ws + (size_t)l * WSZ * 2;  // byte offset if bf16
    const void* W_f = Ws + (size_t)l * WSZ * 4;  // byte offset if fp32
    const void* b_b = bs + (size_t)l * D * 2;
    const void* b_f = bs + (size_t)l * D * 4;
    k_matmul2<<<1024, 256, 0, stream>>>(xbuf, W_b, W_f, dinv, hp, flags, N);
    k_agg2<<<(N + 3) / 4, 256, 0, stream>>>(hp, row_ptr, csr, dinv, b_b, b_f,
                                            flags, xbuf, N);
  }
  k_matmul_final<<<1024, 256, 0, stream>>>(xbuf, Wout, bout, d_out, flags, N);
}

// Round 3
// 458.069 us; speedup vs baseline: 1.0416x; 1.0416x over previous
//
#include <hip/hip_runtime.h>
#include <hip/hip_bf16.h>

#define D 64

// flags[0] = 1 if float tensors are fp32 (else bf16)
// flags[1] = 1 if edge_index is int64 (else int32)

__device__ __forceinline__ float bf16u_to_f32(unsigned short u) {
  union { unsigned int i; float f; } c;
  c.i = ((unsigned int)u) << 16;
  return c.f;
}

__global__ void k_probe(const void* W, const void* ei, int* flags) {
  if (threadIdx.x == 0 && blockIdx.x == 0) {
    const unsigned short* wb = (const unsigned short*)W;
    int big = 0;
    for (int i = 0; i < 512; i++) {
      float v = bf16u_to_f32(wb[i]);
      if (!(fabsf(v) < 100.f)) big = 1;  // NaN also lands here
    }
    flags[0] = big;  // huge magnitudes => data is actually fp32
    const int* e32 = (const int*)ei;
    int anynz = 0;
    for (int i = 1; i < 128; i += 2)
      if (e32[i] != 0) anynz = 1;
    flags[1] = anynz ? 0 : 1;  // all-zero odd slots => int64
  }
}

// ---------------- setup kernels (CSR build + norm) ----------------

__global__ __launch_bounds__(256) void k_count(const void* __restrict__ ei,
                                               const int* __restrict__ flags,
                                               int* __restrict__ deg, int e) {
  int i64 = flags[1];
  int i = blockIdx.x * blockDim.x + threadIdx.x;
  int stride = gridDim.x * blockDim.x;
  if (i64) {
    const long long* dst = (const long long*)ei + e;
    for (; i < e; i += stride) atomicAdd(&deg[(int)dst[i]], 1);
  } else {
    const int* dst = (const int*)ei + e;
    for (; i < e; i += stride) atomicAdd(&deg[dst[i]], 1);
  }
}

#define SCAN_BLOCK 256
#define SCAN_ITEMS 4
__global__ __launch_bounds__(SCAN_BLOCK) void k_local_scan(
    const int* __restrict__ deg, int* __restrict__ row_ptr,
    int* __restrict__ partials, int n) {
  __shared__ int lds[SCAN_BLOCK];
  int base = blockIdx.x * (SCAN_BLOCK * SCAN_ITEMS);
  int t = threadIdx.x;
  int v[SCAN_ITEMS];
  int s = 0;
#pragma unroll
  for (int i = 0; i < SCAN_ITEMS; i++) {
    int idx = base + t * SCAN_ITEMS + i;
    v[i] = (idx < n) ? deg[idx] : 0;
    s += v[i];
  }
  lds[t] = s;
  __syncthreads();
  for (int off = 1; off < SCAN_BLOCK; off <<= 1) {
    int tv = (t >= off) ? lds[t - off] : 0;
    __syncthreads();
    lds[t] += tv;
    __syncthreads();
  }
  int incl = lds[t];
  int excl = incl - s;
  if (t == SCAN_BLOCK - 1) partials[blockIdx.x] = incl;
  int run = excl;
#pragma unroll
  for (int i = 0; i < SCAN_ITEMS; i++) {
    int idx = base + t * SCAN_ITEMS + i;
    if (idx < n) row_ptr[idx] = run;
    run += v[i];
  }
}

__global__ __launch_bounds__(256) void k_scan_partials(int* partials, int nb) {
  __shared__ int lds[256];
  int t = threadIdx.x;
  int v = (t < nb) ? partials[t] : 0;
  lds[t] = v;
  __syncthreads();
  for (int off = 1; off < 256; off <<= 1) {
    int tv = (t >= off) ? lds[t - off] : 0;
    __syncthreads();
    lds[t] += tv;
    __syncthreads();
  }
  if (t < nb) partials[t] = lds[t] - v;
}

__global__ __launch_bounds__(256) void k_finalize(
    int* __restrict__ row_ptr, const int* __restrict__ partials,
    int* __restrict__ cursor, const int* __restrict__ deg,
    float* __restrict__ dinv, int n, int e) {
  int i = blockIdx.x * blockDim.x + threadIdx.x;
  if (i < n) {
    int rp = row_ptr[i] + partials[i >> 10];
    row_ptr[i] = rp;
    cursor[i] = rp;
    dinv[i] = rsqrtf((float)(deg[i] + 1));  // +1 = self loop
    if (i == 0) row_ptr[n] = e;
  }
}

__global__ __launch_bounds__(256) void k_scatter(const void* __restrict__ ei,
                                                 const int* __restrict__ flags,
                                                 int* __restrict__ cursor,
                                                 int* __restrict__ csr, int e) {
  int i64 = flags[1];
  int i = blockIdx.x * blockDim.x + threadIdx.x;
  int stride = gridDim.x * blockDim.x;
  if (i64) {
    const long long* src = (const long long*)ei;
    const long long* dst = src + e;
    for (; i < e; i += stride) {
      int pos = atomicAdd(&cursor[(int)dst[i]], 1);
      csr[pos] = (int)src[i];
    }
  } else {
    const int* src = (const int*)ei;
    const int* dst = src + e;
    for (; i < e; i += stride) {
      int pos = atomicAdd(&cursor[dst[i]], 1);
      csr[pos] = src[i];
    }
  }
}

__global__ __launch_bounds__(256) void k_load_x(const void* __restrict__ in,
                                                const int* __restrict__ flags,
                                                float* __restrict__ out,
                                                int n) {
  int f32 = flags[0];
  int i = blockIdx.x * blockDim.x + threadIdx.x;
  int stride = gridDim.x * blockDim.x;
  if (f32) {
    const float* p = (const float*)in;
    for (; i < n; i += stride) out[i] = p[i];
  } else {
    const __hip_bfloat16* p = (const __hip_bfloat16*)in;
    for (; i < n; i += stride) out[i] = __bfloat162float(p[i]);
  }
}

// ---------------- compute kernels ----------------

// One wave per row (grid-strided). Lane j holds W[:,j] in 64 VGPRs; x-row
// address is wave-uniform (scalar loads). hp output is bf16 (halves the
// gather traffic in k_agg).
__global__ __launch_bounds__(256) void k_matmul2(
    const float* __restrict__ x, const void* __restrict__ Wb,
    const void* __restrict__ Wf, const float* __restrict__ dinv,
    __hip_bfloat16* __restrict__ outh, const int* __restrict__ flags,
    int nrows) {
  int f32 = flags[0];
  int lane = threadIdx.x & 63;
  int wid = threadIdx.x >> 6;
  float w[D];
  if (f32) {
    const float* W = (const float*)Wf;
#pragma unroll
    for (int k = 0; k < D; k++) w[k] = W[k * D + lane];
  } else {
    const __hip_bfloat16* W = (const __hip_bfloat16*)Wb;
#pragma unroll
    for (int k = 0; k < D; k++) w[k] = __bfloat162float(W[k * D + lane]);
  }

  int wave = blockIdx.x * 4 + wid;
  int nwaves = gridDim.x * 4;
  for (int row = wave; row < nrows; row += nwaves) {
    int ur = __builtin_amdgcn_readfirstlane(row);
    const float* xr = x + (size_t)ur * D;
    float a0 = 0.f, a1 = 0.f, a2 = 0.f, a3 = 0.f;
#pragma unroll
    for (int k = 0; k < D; k += 4) {
      a0 = fmaf(xr[k + 0], w[k + 0], a0);
      a1 = fmaf(xr[k + 1], w[k + 1], a1);
      a2 = fmaf(xr[k + 2], w[k + 2], a2);
      a3 = fmaf(xr[k + 3], w[k + 3], a3);
    }
    float acc = (a0 + a1) + (a2 + a3);
    outh[(size_t)ur * D + lane] = __float2bfloat16(dinv[ur] * acc);
  }
}

// Final projection: out = x@W + b, store dtype picked by flag.
__global__ __launch_bounds__(256) void k_matmul_final(
    const float* __restrict__ x, const void* __restrict__ W,
    const void* __restrict__ bias, void* __restrict__ out,
    const int* __restrict__ flags, int nrows) {
  int f32 = flags[0];
  int lane = threadIdx.x & 63;
  int wid = threadIdx.x >> 6;
  float w[D];
  float b;
  if (f32) {
    const float* Wf = (const float*)W;
#pragma unroll
    for (int k = 0; k < D; k++) w[k] = Wf[k * D + lane];
    b = ((const float*)bias)[lane];
  } else {
    const __hip_bfloat16* Wb = (const __hip_bfloat16*)W;
#pragma unroll
    for (int k = 0; k < D; k++) w[k] = __bfloat162float(Wb[k * D + lane]);
    b = __bfloat162float(((const __hip_bfloat16*)bias)[lane]);
  }

  int wave = blockIdx.x * 4 + wid;
  int nwaves = gridDim.x * 4;
  for (int row = wave; row < nrows; row += nwaves) {
    int ur = __builtin_amdgcn_readfirstlane(row);
    const float* xr = x + (size_t)ur * D;
    float a0 = 0.f, a1 = 0.f, a2 = 0.f, a3 = 0.f;
#pragma unroll
    for (int k = 0; k < D; k += 4) {
      a0 = fmaf(xr[k + 0], w[k + 0], a0);
      a1 = fmaf(xr[k + 1], w[k + 1], a1);
      a2 = fmaf(xr[k + 2], w[k + 2], a2);
      a3 = fmaf(xr[k + 3], w[k + 3], a3);
    }
    float r = (a0 + a1) + (a2 + a3) + b;
    size_t idx = (size_t)ur * D + lane;
    if (f32)
      ((float*)out)[idx] = r;
    else
      ((__hip_bfloat16*)out)[idx] = __float2bfloat16(r);
  }
}

// One wave per node. hp rows are bf16 (128B). Half-wave split: lanes 0-31
// process even CSR edges, lanes 32-63 odd edges; each lane loads a ushort2
// (2 features). Unroll 4 => 8 edges in flight per wave. Final __shfl_xor
// merges the two half-accumulators. x' = relu(dinv*(self+sum) + bias).
__global__ __launch_bounds__(256) void k_agg3(
    const __hip_bfloat16* __restrict__ hp, const int* __restrict__ row_ptr,
    const int* __restrict__ csr, const float* __restrict__ dinv,
    const void* __restrict__ bias_b, const void* __restrict__ bias_f,
    const int* __restrict__ flags, float* __restrict__ xout, int n) {
  int f32 = flags[0];
  int lane = threadIdx.x & 63;
  int half = lane >> 5;
  int sub = lane & 31;
  int wid = threadIdx.x >> 6;
  int node = blockIdx.x * 4 + wid;
  if (node >= n) return;
  int un = __builtin_amdgcn_readfirstlane(node);

  int s0 = row_ptr[un];
  int s1 = row_ptr[un + 1];

  const ushort2* hp2 = (const ushort2*)hp;  // row stride = 32 ushort2
  float acc0 = 0.f, acc1 = 0.f;

  for (int base = s0; base < s1; base += 8) {
    int e[4];
    bool m[4];
#pragma unroll
    for (int u = 0; u < 4; u++) {
      int idx = base + half + 2 * u;
      m[u] = idx < s1;
      e[u] = m[u] ? idx : s0;  // s0 valid: loop entered => s1 > s0
    }
    int s[4];
#pragma unroll
    for (int u = 0; u < 4; u++) s[u] = csr[e[u]];
    ushort2 v[4];
#pragma unroll
    for (int u = 0; u < 4; u++) v[u] = hp2[(size_t)s[u] * 32 + sub];
#pragma unroll
    for (int u = 0; u < 4; u++) {
      if (m[u]) {
        acc0 += bf16u_to_f32(v[u].x);
        acc1 += bf16u_to_f32(v[u].y);
      }
    }
  }

  // merge halves: lane l and l^32 hold the same feature pair
  acc0 += __shfl_xor(acc0, 32, 64);
  acc1 += __shfl_xor(acc1, 32, 64);

  // self loop (added once post-merge; both halves now duplicates)
  ushort2 sv = hp2[(size_t)un * 32 + sub];
  acc0 += bf16u_to_f32(sv.x);
  acc1 += bf16u_to_f32(sv.y);

  float b0, b1;
  if (f32) {
    const float* bf = (const float*)bias_f;
    b0 = bf[2 * sub];
    b1 = bf[2 * sub + 1];
  } else {
    const __hip_bfloat16* bb = (const __hip_bfloat16*)bias_b;
    b0 = __bfloat162float(bb[2 * sub]);
    b1 = __bfloat162float(bb[2 * sub + 1]);
  }
  float dv = dinv[un];
  float r0 = fmaxf(fmaf(dv, acc0, b0), 0.f);
  float r1 = fmaxf(fmaf(dv, acc1, b1), 0.f);

  if (half == 0) {
    float2* xo = (float2*)(xout + (size_t)un * D);
    xo[sub] = make_float2(r0, r1);
  }
}

// ---------------- launch ----------------

extern "C" void kernel_launch(void* const* d_in, const int* in_sizes, int n_in,
                              void* d_out, int out_size, void* d_ws,
                              size_t ws_size, hipStream_t stream) {
  const void* x0 = d_in[0];
  const void* ei = d_in[1];
  const char* Ws = (const char*)d_in[2];
  const char* bs = (const char*)d_in[3];
  const void* Wout = d_in[4];
  const void* bout = d_in[5];

  const int N = in_sizes[0] / D;  // 100000
  const int E = in_sizes[1] / 2;  // 1000000
  const int NB = (N + 1023) / 1024;

  char* p = (char*)d_ws;
  auto alloc = [&](size_t bytes) {
    char* r = p;
    p += (bytes + 511) & ~(size_t)511;
    return r;
  };
  int* flags = (int*)alloc(8);
  int* deg = (int*)alloc((size_t)N * 4);
  int* row_ptr = (int*)alloc((size_t)(N + 1) * 4);
  int* cursor = (int*)alloc((size_t)N * 4);
  int* partials = (int*)alloc(1024);
  int* csr = (int*)alloc((size_t)E * 4);
  float* dinv = (float*)alloc((size_t)N * 4);
  __hip_bfloat16* hp = (__hip_bfloat16*)alloc((size_t)N * D * 2);
  float* xbuf = (float*)alloc((size_t)N * D * 4);
  (void)ws_size;
  (void)n_in;
  (void)out_size;

  hipMemsetAsync(deg, 0, (size_t)N * 4, stream);

  k_probe<<<1, 64, 0, stream>>>(Ws, ei, flags);
  k_count<<<1024, 256, 0, stream>>>(ei, flags, deg, E);
  k_local_scan<<<NB, 256, 0, stream>>>(deg, row_ptr, partials, N);
  k_scan_partials<<<1, 256, 0, stream>>>(partials, NB);
  k_finalize<<<(N + 255) / 256, 256, 0, stream>>>(row_ptr, partials, cursor,
                                                  deg, dinv, N, E);
  k_scatter<<<1024, 256, 0, stream>>>(ei, flags, cursor, csr, E);
  k_load_x<<<2048, 256, 0, stream>>>(x0, flags, xbuf, N * D);

  const size_t WSZ = (size_t)D * D;
  for (int l = 0; l < 3; ++l) {
    const void* W_b = Ws + (size_t)l * WSZ * 2;  // byte offset if bf16
    const void* W_f = Ws + (size_t)l * WSZ * 4;  // byte offset if fp32
    const void* b_b = bs + (size_t)l * D * 2;
    const void* b_f = bs + (size_t)l * D * 4;
    k_matmul2<<<1024, 256, 0, stream>>>(xbuf, W_b, W_f, dinv, hp, flags, N);
    k_agg3<<<(N + 3) / 4, 256, 0, stream>>>(hp, row_ptr, csr, dinv, b_b, b_f,
                                            flags, xbuf, N);
  }
  k_matmul_final<<<1024, 256, 0, stream>>>(xbuf, Wout, bout, d_out, flags, N);
}